// Round 4
// baseline (1070.911 us; speedup 1.0000x reference)
//
#include <hip/hip_runtime.h>
#include <hip/hip_bf16.h>
#include <math.h>

// Problem constants
#define BATCH   128
#define DMODEL  1024
#define NHEADS  16
#define HEADDIM 64
#define DFF     4096
#define MEMLEN  1024
#define SPLIT   16         // flash-decode m-splits (2048 blocks = 8/CU resident)
#define CHUNK   (MEMLEN / SPLIT)
#define QSPLIT  4          // split-K for Wq / Wo (kchunk 256, 8 iters, 128 blocks)
#define F1SPLIT 2          // split-K for ff1    (kchunk 512, 16 iters, 256 blocks)
#define F2SPLIT 8          // split-K for ff2    (kchunk 512, 16 iters, 256 blocks)

typedef __attribute__((ext_vector_type(8))) __bf16 bf16x8;
typedef __attribute__((ext_vector_type(4))) __bf16 bf16x4;
typedef __attribute__((ext_vector_type(4))) float  f32x4;

// ---------------------------------------------------------------------------
// Split-K GEMM: Cpart[z][M x N] = A[M x kchunk] @ W + (z==0 ? bias : 0).
// Grid (N/64, M/64, ZSPLIT), 256 threads = 4 waves. Tile BM=64,BN=64,BK=32.
// Double-buffered LDS, register prefetch, ONE barrier per K-step.
// ABF16:  A is bf16 (one bf16x8 load, no cvt).
// APARTS: fp32-A partial buffers to sum while staging (ff2 reads ff1's 2).
// RELU:   applied to the summed fp32 A before cvt (moves ff1's activation
//         into ff2's A-stage).
// LDS row stride 56 bf16 (112 B): b128-aligned, 2-way bank alias = free.
// ---------------------------------------------------------------------------
template<int ABF16, int APARTS, int RELU>
__global__ __launch_bounds__(256) void gemm_k(
    const float* __restrict__ Af, size_t aPartStride,
    const __bf16* __restrict__ Ab,
    const float* __restrict__ W, const float* __restrict__ bias,
    float* __restrict__ C, int N, int K, int kchunk)
{
    const int t    = threadIdx.x;
    const int lane = t & 63;
    const int w    = t >> 6;
    const int n0   = blockIdx.x * 64;
    const int m0   = blockIdx.y * 64;
    const int z    = blockIdx.z;
    const int kbeg = z * kchunk;

    __shared__ __bf16 As[2][64 * 56];
    __shared__ __bf16 Bs[2][64 * 56];

    const int ar = t >> 2, ac = (t & 3) * 8;   // A staging coords
    const int bn = t & 63, bk = w * 8;         // B staging coords (transposed)
    const int q = lane >> 4, l15 = lane & 15;  // fragment coords

    f32x4 acc[4] = {f32x4{0,0,0,0}, f32x4{0,0,0,0}, f32x4{0,0,0,0}, f32x4{0,0,0,0}};

    const float* wB   = W + (size_t)(kbeg + bk) * N + n0 + bn;
    const size_t aOff = (size_t)(m0 + ar) * K + kbeg + ac;

    // ---- prologue: stage tile 0 into buffer 0
    {
        bf16x8 av;
        if constexpr (ABF16) {
            av = *(const bf16x8*)(Ab + aOff);
        } else {
            const float* ap = Af + aOff;
            float4 a0 = *(const float4*)ap, a1 = *(const float4*)(ap + 4);
            float va[8] = {a0.x, a0.y, a0.z, a0.w, a1.x, a1.y, a1.z, a1.w};
            if constexpr (APARTS == 2) {
                const float* a2 = ap + aPartStride;
                float4 y0 = *(const float4*)a2, y1 = *(const float4*)(a2 + 4);
                va[0]+=y0.x; va[1]+=y0.y; va[2]+=y0.z; va[3]+=y0.w;
                va[4]+=y1.x; va[5]+=y1.y; va[6]+=y1.z; va[7]+=y1.w;
            }
            #pragma unroll
            for (int j = 0; j < 8; j++) {
                float v = va[j];
                if (RELU) v = fmaxf(v, 0.0f);
                av[j] = (__bf16)v;
            }
        }
        bf16x8 bv;
        #pragma unroll
        for (int j = 0; j < 8; j++) bv[j] = (__bf16)wB[(size_t)j * N];
        *(bf16x8*)&As[0][ar * 56 + ac] = av;
        *(bf16x8*)&Bs[0][bn * 56 + bk] = bv;
    }
    __syncthreads();

    const int iters = kchunk >> 5;
    int cur = 0;
    for (int it = 1; it < iters; ++it) {
        // ---- prefetch next tile (issued before MFMAs; HBM latency hides)
        bf16x8 avn;
        float ax[8];
        if constexpr (ABF16) {
            avn = *(const bf16x8*)(Ab + aOff + it * 32);
        } else {
            const float* ap = Af + aOff + it * 32;
            float4 a0 = *(const float4*)ap, a1 = *(const float4*)(ap + 4);
            ax[0]=a0.x; ax[1]=a0.y; ax[2]=a0.z; ax[3]=a0.w;
            ax[4]=a1.x; ax[5]=a1.y; ax[6]=a1.z; ax[7]=a1.w;
            if constexpr (APARTS == 2) {
                const float* a2 = ap + aPartStride;
                float4 y0 = *(const float4*)a2, y1 = *(const float4*)(a2 + 4);
                ax[0]+=y0.x; ax[1]+=y0.y; ax[2]+=y0.z; ax[3]+=y0.w;
                ax[4]+=y1.x; ax[5]+=y1.y; ax[6]+=y1.z; ax[7]+=y1.w;
            }
        }
        float br[8];
        const float* wp = wB + (size_t)(it * 32) * N;
        #pragma unroll
        for (int j = 0; j < 8; j++) br[j] = wp[(size_t)j * N];

        // ---- compute current tile
        bf16x8 af = *(const bf16x8*)&As[cur][(w * 16 + l15) * 56 + q * 8];
        #pragma unroll
        for (int c = 0; c < 4; c++) {
            bf16x8 bfv = *(const bf16x8*)&Bs[cur][(c * 16 + l15) * 56 + q * 8];
            acc[c] = __builtin_amdgcn_mfma_f32_16x16x32_bf16(af, bfv, acc[c], 0, 0, 0);
        }

        // ---- stage next tile
        if constexpr (!ABF16) {
            #pragma unroll
            for (int j = 0; j < 8; j++) {
                float v = ax[j];
                if (RELU) v = fmaxf(v, 0.0f);
                avn[j] = (__bf16)v;
            }
        }
        bf16x8 bvn;
        #pragma unroll
        for (int j = 0; j < 8; j++) bvn[j] = (__bf16)br[j];
        *(bf16x8*)&As[cur ^ 1][ar * 56 + ac] = avn;
        *(bf16x8*)&Bs[cur ^ 1][bn * 56 + bk] = bvn;
        __syncthreads();
        cur ^= 1;
    }

    // ---- final tile
    {
        bf16x8 af = *(const bf16x8*)&As[cur][(w * 16 + l15) * 56 + q * 8];
        #pragma unroll
        for (int c = 0; c < 4; c++) {
            bf16x8 bfv = *(const bf16x8*)&Bs[cur][(c * 16 + l15) * 56 + q * 8];
            acc[c] = __builtin_amdgcn_mfma_f32_16x16x32_bf16(af, bfv, acc[c], 0, 0, 0);
        }
    }

    // ---- epilogue: C/D layout col=lane&15, row=(lane>>4)*4+reg [m89]
    float* Cp = C + (size_t)z * ((size_t)BATCH * N);
    #pragma unroll
    for (int c = 0; c < 4; c++) {
        const int col = n0 + c * 16 + l15;
        const float bb = (z == 0) ? bias[col] : 0.0f;
        #pragma unroll
        for (int r = 0; r < 4; r++) {
            const int row = m0 + w * 16 + q * 4 + r;
            Cp[(size_t)row * N + col] = acc[c][r] + bb;
        }
    }
}

// ---------------------------------------------------------------------------
// Flash-decode attention partials. Grid (SPLIT, BATCH), 256 threads.
// Thread t owns dims [4t,4t+4) -> head h = t>>4. Sums the QSPLIT q-partials
// inline (cheap: 4 x 16B per thread). Scores bounded
// (|q.k/8| + |alibi| < ~8) => direct exp, no online-max chain.
// ---------------------------------------------------------------------------
__global__ __launch_bounds__(256) void attn_partial_k(
    const float* __restrict__ qpart, const float* __restrict__ Kd,
    const float* __restrict__ Vd, const float* __restrict__ alibi,
    float* __restrict__ pacc, float* __restrict__ pl)
{
    const int s = blockIdx.x;
    const int b = blockIdx.y;
    const int t = threadIdx.x;
    const int h = t >> 4;

    float4 qv = {0.f, 0.f, 0.f, 0.f};
    #pragma unroll
    for (int z = 0; z < QSPLIT; z++) {
        const float4 qp = *(const float4*)
            &qpart[(size_t)z * (BATCH * DMODEL) + (size_t)b * DMODEL + 4 * t];
        qv.x += qp.x; qv.y += qp.y; qv.z += qp.z; qv.w += qp.w;
    }
    const float scale = 0.125f;   // 1/sqrt(64)
    qv.x *= scale; qv.y *= scale; qv.z *= scale; qv.w *= scale;

    float  l   = 0.0f;
    f32x4  acc = {0.f, 0.f, 0.f, 0.f};

    const size_t base = (size_t)b * MEMLEN * DMODEL + 4 * t;
    const float* __restrict__ ali = alibi + (size_t)h * MEMLEN + s * CHUNK;
    const size_t off0 = base + (size_t)(s * CHUNK) * DMODEL;

    #pragma unroll 4
    for (int i = 0; i < CHUNK; i++) {
        const size_t off = off0 + (size_t)i * DMODEL;
        const float4 kv = *(const float4*)&Kd[off];
        const float4 vv = *(const float4*)&Vd[off];
        float d = kv.x * qv.x + kv.y * qv.y + kv.z * qv.z + kv.w * qv.w;
        d += __shfl_xor(d, 1);
        d += __shfl_xor(d, 2);
        d += __shfl_xor(d, 4);
        d += __shfl_xor(d, 8);
        const float pw = __expf(d + ali[i]);
        l += pw;
        acc.x += pw * vv.x;
        acc.y += pw * vv.y;
        acc.z += pw * vv.z;
        acc.w += pw * vv.w;
    }
    *(f32x4*)&pacc[((size_t)(b * SPLIT + s)) * DMODEL + 4 * t] = acc;
    if ((t & 15) == 0) pl[(b * SPLIT + s) * NHEADS + h] = l;
}

// Combine SPLIT partials -> attn (bf16, ready as Wo's A operand). Grid 128.
__global__ __launch_bounds__(256) void attn_combine_k(
    const float* __restrict__ pacc, const float* __restrict__ pl,
    __bf16* __restrict__ attnb)
{
    const int b = blockIdx.x;
    const int t = threadIdx.x;
    const int h = t >> 4;

    float  L   = 0.0f;
    float4 acc = {0.f, 0.f, 0.f, 0.f};
    #pragma unroll
    for (int s = 0; s < SPLIT; s++) {
        L += pl[(b * SPLIT + s) * NHEADS + h];
        const float4 pa = *(const float4*)
            &pacc[((size_t)(b * SPLIT + s)) * DMODEL + 4 * t];
        acc.x += pa.x; acc.y += pa.y; acc.z += pa.z; acc.w += pa.w;
    }
    const float inv = 1.0f / L;
    bf16x4 o;
    o[0] = (__bf16)(acc.x * inv); o[1] = (__bf16)(acc.y * inv);
    o[2] = (__bf16)(acc.z * inv); o[3] = (__bf16)(acc.w * inv);
    *(bf16x4*)&attnb[(size_t)b * DMODEL + 4 * t] = o;
}

// out = LN(x + sum_z parts[z]) * g + be; optional bf16 copy. Grid 128.
template<int NPARTS, bool WRITE_BF16>
__global__ __launch_bounds__(256) void ln_k(
    const float* __restrict__ xres, const float* __restrict__ parts,
    const float* __restrict__ g, const float* __restrict__ be,
    float* __restrict__ of32, __bf16* __restrict__ obf)
{
    const int b = blockIdx.x;
    const int t = threadIdx.x;
    float4 sv = *(const float4*)&xres[(size_t)b * DMODEL + 4 * t];
    #pragma unroll
    for (int z = 0; z < NPARTS; z++) {
        const float4 yv = *(const float4*)
            &parts[(size_t)z * (BATCH * DMODEL) + (size_t)b * DMODEL + 4 * t];
        sv.x += yv.x; sv.y += yv.y; sv.z += yv.z; sv.w += yv.w;
    }
    float sum = sv.x + sv.y + sv.z + sv.w;
    float sq  = sv.x * sv.x + sv.y * sv.y + sv.z * sv.z + sv.w * sv.w;
    #pragma unroll
    for (int mask = 1; mask < 64; mask <<= 1) {
        sum += __shfl_xor(sum, mask);
        sq  += __shfl_xor(sq, mask);
    }
    __shared__ float red[8];
    const int w = t >> 6;
    if ((t & 63) == 0) { red[w * 2] = sum; red[w * 2 + 1] = sq; }
    __syncthreads();
    sum = red[0] + red[2] + red[4] + red[6];
    sq  = red[1] + red[3] + red[5] + red[7];

    const float mu  = sum * (1.0f / DMODEL);
    const float var = sq * (1.0f / DMODEL) - mu * mu;
    const float rs  = rsqrtf(var + 1e-5f);

    const float4 gv  = *(const float4*)&g[4 * t];
    const float4 bev = *(const float4*)&be[4 * t];
    float4 o;
    o.x = (sv.x - mu) * rs * gv.x + bev.x;
    o.y = (sv.y - mu) * rs * gv.y + bev.y;
    o.z = (sv.z - mu) * rs * gv.z + bev.z;
    o.w = (sv.w - mu) * rs * gv.w + bev.w;
    *(float4*)&of32[(size_t)b * DMODEL + 4 * t] = o;
    if constexpr (WRITE_BF16) {
        bf16x4 ob;
        ob[0] = (__bf16)o.x; ob[1] = (__bf16)o.y;
        ob[2] = (__bf16)o.z; ob[3] = (__bf16)o.w;
        *(bf16x4*)&obf[(size_t)b * DMODEL + 4 * t] = ob;
    }
}

// ---------------------------------------------------------------------------
extern "C" void kernel_launch(void* const* d_in, const int* in_sizes, int n_in,
                              void* d_out, int out_size, void* d_ws, size_t ws_size,
                              hipStream_t stream)
{
    const float* x   = (const float*)d_in[0];
    const float* mk  = (const float*)d_in[1];
    const float* mv  = (const float*)d_in[2];
    const float* ab  = (const float*)d_in[3];
    const float* Wq  = (const float*)d_in[4];
    const float* bq  = (const float*)d_in[5];
    const float* Wo  = (const float*)d_in[6];
    const float* bo  = (const float*)d_in[7];
    const float* W1  = (const float*)d_in[8];
    const float* b1  = (const float*)d_in[9];
    const float* W2  = (const float*)d_in[10];
    const float* b2  = (const float*)d_in[11];
    const float* g1  = (const float*)d_in[12];
    const float* be1 = (const float*)d_in[13];
    const float* g2  = (const float*)d_in[14];
    const float* be2 = (const float*)d_in[15];
    float* out = (float*)d_out;

    // Workspace layout (floats); every buffer fully written before read.
    float* wsf      = (float*)d_ws;
    float* qpart    = wsf;                 // 4 x 131072 = 524288
    float* tmppart  = wsf + 524288;        // 4 x 131072 = 524288
    float* hbuf     = wsf + 1048576;       // 131072
    float* ffbpart  = wsf + 1179648;       // 2 x 524288 = 1048576
    float* tmp2part = wsf + 2228224;       // 8 x 131072 = 1048576
    float* pacc     = wsf + 3276800;       // 16 x 131072 = 2097152
    float* pl       = wsf + 5373952;       // 32768
    __bf16* attnb   = (__bf16*)(wsf + 5406720);   // 131072 bf16
    __bf16* hbf     = (__bf16*)(wsf + 5472256);   // 131072 bf16

    // 1. q partials = x @ Wq + bq  (fp32 A; 128 blocks)
    gemm_k<0, 1, 0><<<dim3(16, 2, QSPLIT), 256, 0, stream>>>(
        x, 0, nullptr, Wq, bq, qpart, DMODEL, DMODEL, DMODEL / QSPLIT);
    // 2. flash-decode attention partials (the 1 GB K/V stream; 2048 blocks)
    attn_partial_k<<<dim3(SPLIT, BATCH), 256, 0, stream>>>(
        qpart, mk, mv, ab, pacc, pl);
    // 3. combine -> attn (bf16)
    attn_combine_k<<<BATCH, 256, 0, stream>>>(pacc, pl, attnb);
    // 4. attn-proj partials = attn @ Wo + bo  (bf16 A; 128 blocks)
    gemm_k<1, 1, 0><<<dim3(16, 2, QSPLIT), 256, 0, stream>>>(
        nullptr, 0, attnb, Wo, bo, tmppart, DMODEL, DMODEL, DMODEL / QSPLIT);
    // 5. h = LN(x + attn_proj); fp32 (residual) + bf16 (ff1 A operand)
    ln_k<QSPLIT, true><<<BATCH, 256, 0, stream>>>(
        x, tmppart, g1, be1, hbuf, hbf);
    // 6. ff1 partials = h @ W1 + b1  (bf16 A; 256 blocks; pre-activation)
    gemm_k<1, 1, 0><<<dim3(64, 2, F1SPLIT), 256, 0, stream>>>(
        nullptr, 0, hbf, W1, b1, ffbpart, DFF, DMODEL, DMODEL / F1SPLIT);
    // 7. ff2 partials = relu(sum ffbpart) @ W2 + b2  (fp32 A x2 + relu in-stage)
    gemm_k<0, 2, 1><<<dim3(16, 2, F2SPLIT), 256, 0, stream>>>(
        ffbpart, (size_t)BATCH * DFF, nullptr, W2, b2, tmp2part,
        DMODEL, DFF, DFF / F2SPLIT);
    // 8. out = LN(h + ff2)
    ln_k<F2SPLIT, false><<<BATCH, 256, 0, stream>>>(
        hbuf, tmp2part, g2, be2, out, nullptr);
}